// Round 1
// baseline (23596.695 us; speedup 1.0000x reference)
//
#include <hip/hip_runtime.h>
#include <hip/hip_cooperative_groups.h>
#include <cstddef>

namespace cg = cooperative_groups;

// Problem dims
constexpr int kB = 32;    // batch
constexpr int kT = 512;   // time steps
constexpr int kF = 513;   // input features
constexpr int kH = 512;   // hidden

// ---------------------------------------------------------------------------
// Kernel 1: transpose x [B][T][F] -> xT [T][F][B]  (coalesced reads+writes)
// ---------------------------------------------------------------------------
__global__ __launch_bounds__(256) void transpose_x(const float* __restrict__ x,
                                                   float* __restrict__ xT) {
  __shared__ float s[32][33];
  const int f0 = blockIdx.x * 32;
  const int t  = blockIdx.y;
  const int i  = threadIdx.x;
  const int lo = i & 31;
  const int g8 = i >> 5;  // 0..7
#pragma unroll
  for (int q = 0; q < 4; ++q) {
    const int b = g8 * 4 + q;
    const int f = f0 + lo;
    float v = 0.f;
    if (f < kF) v = x[((size_t)b * kT + t) * kF + f];
    s[b][lo] = v;
  }
  __syncthreads();
#pragma unroll
  for (int q = 0; q < 4; ++q) {
    const int fo = g8 * 4 + q;
    const int f = f0 + fo;
    if (f < kF) xT[(size_t)t * (kF * kB) + (size_t)f * kB + lo] = s[lo][fo];
  }
}

// ---------------------------------------------------------------------------
// Kernel 2: persistent cooperative GRU.
// Skewed schedule: phase p does L1(t=p), L2(t=p-1), L3(t=p-2) -- all depend
// only on phase p-1 results => exactly ONE grid.sync per phase (514 total).
// h buffers stored transposed [H][B], ping-pong by phase parity.
// Each block owns 2 h-columns per layer (6 gate rows). Thread decomposition:
// tid -> (b-quad 0..7, jj 0..1, ks 0..31 k-chunks); LDS reduce over ks.
// ---------------------------------------------------------------------------
struct GruParams {
  const float* xT;       // [T][F][B]
  const float* wih[3];   // [3H][KA] row-major (KA=513 for L0 else 512)
  const float* whh[3];   // [3H][H]
  const float* bih[3];
  const float* bhh[3];
  float* h[3][2];        // hT ping-pong buffers [H][B]
  float* out_h;          // [B*T][H]
};

__global__ __launch_bounds__(512) void gru_seq(GruParams P) {
  cg::grid_group grid = cg::this_grid();
  __shared__ float part[2][6][32][36];  // [seg(i/h)][gate-row][b][ks(+pad)]
  __shared__ float red[2][6][32];

  const int tid = threadIdx.x;
  const int j0 = blockIdx.x * 2;       // this block's first h-column
  const int b4 = (tid & 7) * 4;        // batch quad base
  const int jj = (tid >> 3) & 1;       // which of the 2 columns
  const int ks = tid >> 4;             // 0..31 k-chunk id
  const int j  = j0 + jj;

  for (int p = 0; p < kT + 2; ++p) {
    const int wp = p & 1;              // write parity
    const int rp = wp ^ 1;             // read parity
#pragma unroll 1
    for (int L = 0; L < 3; ++L) {
      const int t = p - L;
      const bool valid = (t >= 0) && (t < kT);
      if (valid) {
        const int KA = (L == 0) ? kF : kH;
        const float* inA  = (L == 0) ? (P.xT + (size_t)t * (kF * kB))
                                     : P.h[L - 1][rp];
        const float* hOld = P.h[L][rp];
        const float* wa0 = P.wih[L] + (size_t)(0 * kH + j) * KA;
        const float* wa1 = P.wih[L] + (size_t)(1 * kH + j) * KA;
        const float* wa2 = P.wih[L] + (size_t)(2 * kH + j) * KA;
        const float* wh0 = P.whh[L] + (size_t)(0 * kH + j) * kH;
        const float* wh1 = P.whh[L] + (size_t)(1 * kH + j) * kH;
        const float* wh2 = P.whh[L] + (size_t)(2 * kH + j) * kH;

        float acc[3][4];
        // ---- segment A: input-side dot (w_ih . in) ----
#pragma unroll
        for (int g = 0; g < 3; ++g)
#pragma unroll
          for (int q = 0; q < 4; ++q) acc[g][q] = 0.f;
        {
          const int CA = (KA + 31) >> 5;
          const int k0 = ks * CA;
          const int k1 = (k0 + CA < KA) ? (k0 + CA) : KA;
#pragma unroll 4
          for (int k = k0; k < k1; ++k) {
            const float4 iv = *reinterpret_cast<const float4*>(inA + (size_t)k * kB + b4);
            const float w0 = wa0[k], w1 = wa1[k], w2 = wa2[k];
            acc[0][0] += w0 * iv.x; acc[0][1] += w0 * iv.y; acc[0][2] += w0 * iv.z; acc[0][3] += w0 * iv.w;
            acc[1][0] += w1 * iv.x; acc[1][1] += w1 * iv.y; acc[1][2] += w1 * iv.z; acc[1][3] += w1 * iv.w;
            acc[2][0] += w2 * iv.x; acc[2][1] += w2 * iv.y; acc[2][2] += w2 * iv.z; acc[2][3] += w2 * iv.w;
          }
        }
#pragma unroll
        for (int g = 0; g < 3; ++g)
#pragma unroll
          for (int q = 0; q < 4; ++q) part[0][g * 2 + jj][b4 + q][ks] = acc[g][q];

        // ---- segment B: hidden-side dot (w_hh . h_old) ----
#pragma unroll
        for (int g = 0; g < 3; ++g)
#pragma unroll
          for (int q = 0; q < 4; ++q) acc[g][q] = 0.f;
        {
          const int k0 = ks * 16;
#pragma unroll 4
          for (int kk = 0; kk < 16; ++kk) {
            const int k = k0 + kk;
            const float4 iv = *reinterpret_cast<const float4*>(hOld + (size_t)k * kB + b4);
            const float w0 = wh0[k], w1 = wh1[k], w2 = wh2[k];
            acc[0][0] += w0 * iv.x; acc[0][1] += w0 * iv.y; acc[0][2] += w0 * iv.z; acc[0][3] += w0 * iv.w;
            acc[1][0] += w1 * iv.x; acc[1][1] += w1 * iv.y; acc[1][2] += w1 * iv.z; acc[1][3] += w1 * iv.w;
            acc[2][0] += w2 * iv.x; acc[2][1] += w2 * iv.y; acc[2][2] += w2 * iv.z; acc[2][3] += w2 * iv.w;
          }
        }
#pragma unroll
        for (int g = 0; g < 3; ++g)
#pragma unroll
          for (int q = 0; q < 4; ++q) part[1][g * 2 + jj][b4 + q][ks] = acc[g][q];
      }
      __syncthreads();
      // ---- reduce over ks: 192 threads, one per (gate-row, b) ----
      if (valid && tid < 192) {
        const int rr = tid >> 5, bb = tid & 31;
        float sI = 0.f, sH = 0.f;
#pragma unroll
        for (int kq = 0; kq < 32; kq += 4) {
          const float4 v0 = *reinterpret_cast<const float4*>(&part[0][rr][bb][kq]);
          const float4 v1 = *reinterpret_cast<const float4*>(&part[1][rr][bb][kq]);
          sI += (v0.x + v0.y) + (v0.z + v0.w);
          sH += (v1.x + v1.y) + (v1.z + v1.w);
        }
        red[0][rr][bb] = sI;
        red[1][rr][bb] = sH;
      }
      __syncthreads();
      // ---- gate combine: 64 threads, one per (jj, b) ----
      if (valid && tid < 64) {
        const int bb = tid & 31, j2 = tid >> 5;
        const int jc = j0 + j2;
        const float* bi = P.bih[L];
        const float* bh = P.bhh[L];
        const float iR = red[0][0 + j2][bb] + bi[0 * kH + jc];
        const float hR = red[1][0 + j2][bb] + bh[0 * kH + jc];
        const float iZ = red[0][2 + j2][bb] + bi[1 * kH + jc];
        const float hZ = red[1][2 + j2][bb] + bh[1 * kH + jc];
        const float iN = red[0][4 + j2][bb] + bi[2 * kH + jc];
        const float hN = red[1][4 + j2][bb] + bh[2 * kH + jc];
        const float rg = 1.f / (1.f + expf(-(iR + hR)));
        const float zg = 1.f / (1.f + expf(-(iZ + hZ)));
        const float ng = tanhf(iN + rg * hN);
        const float ho = P.h[L][rp][jc * kB + bb];
        const float hn = (1.f - zg) * ng + zg * ho;
        P.h[L][wp][jc * kB + bb] = hn;
        if (L == 2) P.out_h[((size_t)bb * kT + t) * kH + jc] = hn;
      }
      __syncthreads();
    }
    grid.sync();
  }
}

// ---------------------------------------------------------------------------
// Kernel 3: fused head. C1 = out_h @ w_l1^T, C2 = out_h @ w_l2^T computed in
// the same tile so the mask ratio + x multiply fuse in the epilogue.
// 64x64x16 tiles, 256 threads, 4x4 microtile per thread.
// ---------------------------------------------------------------------------
__global__ __launch_bounds__(256) void out_mask(
    const float* __restrict__ A,   // out_h [B*T][H]
    const float* __restrict__ w1, const float* __restrict__ bl1,
    const float* __restrict__ w2, const float* __restrict__ bl2,
    const float* __restrict__ x,   // [B*T][F]
    float* __restrict__ o1, float* __restrict__ o2) {
  __shared__ float As[16][68], W1s[16][68], W2s[16][68];
  const int tid = threadIdx.x;
  const int n0 = blockIdx.x * 64;
  const int m0 = blockIdx.y * 64;
  const int tn = tid & 15, tm = tid >> 4;
  const int lr = tid >> 2;        // 0..63 tile row for loading
  const int lk = (tid & 3) * 4;   // k quad for loading

  float ac1[4][4], ac2[4][4];
#pragma unroll
  for (int mm = 0; mm < 4; ++mm)
#pragma unroll
    for (int nn = 0; nn < 4; ++nn) { ac1[mm][nn] = 0.f; ac2[mm][nn] = 0.f; }

  for (int k0 = 0; k0 < kH; k0 += 16) {
    const float4 av = *reinterpret_cast<const float4*>(A + (size_t)(m0 + lr) * kH + k0 + lk);
    const int fA = n0 + lr;
    float4 wv1 = make_float4(0.f, 0.f, 0.f, 0.f);
    float4 wv2 = make_float4(0.f, 0.f, 0.f, 0.f);
    if (fA < kF) {
      wv1 = *reinterpret_cast<const float4*>(w1 + (size_t)fA * kH + k0 + lk);
      wv2 = *reinterpret_cast<const float4*>(w2 + (size_t)fA * kH + k0 + lk);
    }
    __syncthreads();
    As[lk + 0][lr] = av.x;  As[lk + 1][lr] = av.y;  As[lk + 2][lr] = av.z;  As[lk + 3][lr] = av.w;
    W1s[lk + 0][lr] = wv1.x; W1s[lk + 1][lr] = wv1.y; W1s[lk + 2][lr] = wv1.z; W1s[lk + 3][lr] = wv1.w;
    W2s[lk + 0][lr] = wv2.x; W2s[lk + 1][lr] = wv2.y; W2s[lk + 2][lr] = wv2.z; W2s[lk + 3][lr] = wv2.w;
    __syncthreads();
#pragma unroll
    for (int kk = 0; kk < 16; ++kk) {
      const float4 a = *reinterpret_cast<const float4*>(&As[kk][tm * 4]);
      const float4 u = *reinterpret_cast<const float4*>(&W1s[kk][tn * 4]);
      const float4 v = *reinterpret_cast<const float4*>(&W2s[kk][tn * 4]);
      const float aa[4] = {a.x, a.y, a.z, a.w};
      const float uu[4] = {u.x, u.y, u.z, u.w};
      const float vv[4] = {v.x, v.y, v.z, v.w};
#pragma unroll
      for (int mm = 0; mm < 4; ++mm)
#pragma unroll
        for (int nn = 0; nn < 4; ++nn) {
          ac1[mm][nn] += aa[mm] * uu[nn];
          ac2[mm][nn] += aa[mm] * vv[nn];
        }
    }
  }
#pragma unroll
  for (int mm = 0; mm < 4; ++mm) {
    const int row = m0 + tm * 4 + mm;
#pragma unroll
    for (int nn = 0; nn < 4; ++nn) {
      const int f = n0 + tn * 4 + nn;
      if (f < kF) {
        const float s1 = fmaxf(ac1[mm][nn] + bl1[f], 0.f);
        const float s2 = fmaxf(ac2[mm][nn] + bl2[f], 0.f);
        const float inv = 1.f / (s1 + s2 + 1e-16f);
        const float xv = x[(size_t)row * kF + f];
        o1[(size_t)row * kF + f] = s1 * inv * xv;
        o2[(size_t)row * kF + f] = s2 * inv * xv;
      }
    }
  }
}

// ---------------------------------------------------------------------------
extern "C" void kernel_launch(void* const* d_in, const int* in_sizes, int n_in,
                              void* d_out, int out_size, void* d_ws, size_t ws_size,
                              hipStream_t stream) {
  const float* x = (const float*)d_in[0];
  GruParams P;
  P.wih[0] = (const float*)d_in[1];  P.whh[0] = (const float*)d_in[2];
  P.bih[0] = (const float*)d_in[3];  P.bhh[0] = (const float*)d_in[4];
  P.wih[1] = (const float*)d_in[5];  P.whh[1] = (const float*)d_in[6];
  P.bih[1] = (const float*)d_in[7];  P.bhh[1] = (const float*)d_in[8];
  P.wih[2] = (const float*)d_in[9];  P.whh[2] = (const float*)d_in[10];
  P.bih[2] = (const float*)d_in[11]; P.bhh[2] = (const float*)d_in[12];
  const float* w_l1 = (const float*)d_in[13];
  const float* b_l1 = (const float*)d_in[14];
  const float* w_l2 = (const float*)d_in[15];
  const float* b_l2 = (const float*)d_in[16];

  float* ws = (float*)d_ws;
  // ws layout (floats): 6 x hT[512*32] | xT[512*513*32] | out_h[16384*512]
  for (int l = 0; l < 3; ++l)
    for (int pp = 0; pp < 2; ++pp)
      P.h[l][pp] = ws + (size_t)(l * 2 + pp) * (kH * kB);
  float* xT = ws + (size_t)6 * (kH * kB);
  float* out_h = xT + (size_t)kT * kF * kB;
  P.xT = xT;
  P.out_h = out_h;

  // zero initial hidden states (both parities) -- required every call since
  // the harness does not re-poison between replays
  hipMemsetAsync(ws, 0, (size_t)6 * kH * kB * sizeof(float), stream);

  transpose_x<<<dim3(17, kT), 256, 0, stream>>>(x, xT);

  void* args[] = { (void*)&P };
  hipLaunchCooperativeKernel((void*)gru_seq, dim3(256), dim3(512), args, 0u, stream);

  float* o1 = (float*)d_out;
  float* o2 = o1 + (size_t)kB * kT * kF;
  out_mask<<<dim3(9, 256), 256, 0, stream>>>(out_h, w_l1, b_l1, w_l2, b_l2, x, o1, o2);
}

// Round 3
// 15113.457 us; speedup vs baseline: 1.5613x; 1.5613x over previous
//
#include <hip/hip_runtime.h>
#include <cstddef>

// Problem dims
constexpr int kB = 32;    // batch
constexpr int kT = 512;   // time steps
constexpr int kF = 513;   // input features
constexpr int kH = 512;   // hidden
constexpr int kPhases = kT + 2;  // skewed schedule

// ---------------------------------------------------------------------------
// Kernel 1: transpose x [B][T][F] -> xq [T][8][F][4]  (quad-blocked batch)
// ---------------------------------------------------------------------------
__global__ __launch_bounds__(256) void transpose_x(const float* __restrict__ x,
                                                   float* __restrict__ xq) {
  __shared__ float s[32][33];
  const int f0 = blockIdx.x * 32;
  const int t  = blockIdx.y;
  const int i  = threadIdx.x;
  const int lo = i & 31;
  const int g8 = i >> 5;  // 0..7
#pragma unroll
  for (int qq = 0; qq < 4; ++qq) {
    const int b = g8 * 4 + qq;
    const int f = f0 + lo;
    float v = 0.f;
    if (f < kF) v = x[((size_t)b * kT + t) * kF + f];
    s[b][lo] = v;
  }
  __syncthreads();
  const int r  = lo & 3;
  const int fl = lo >> 2;  // 0..7
#pragma unroll
  for (int it = 0; it < 4; ++it) {
    const int f = f0 + fl + 8 * it;
    if (f < kF)
      xq[((size_t)(t * 8 + g8) * kF + f) * 4 + r] = s[g8 * 4 + r][fl + 8 * it];
  }
}

// ---------------------------------------------------------------------------
// Kernel 2: persistent GRU, skewed schedule (514 phases), LDS-resident
// weights read as ds_read_b128, shuffle butterfly reduce, two-level grid
// barrier. 256 blocks x 512 thr; block owns 2 h-columns.
// Lane k-slice: k = 4*ks + 128*i (contiguous quads -> b128 weight reads and
// 64B-contiguous input loads per lane).
// ---------------------------------------------------------------------------
struct GruParams {
  const float* xq;       // [T][8][513][4]
  const float* wih[3];   // [3H][KA]
  const float* whh[3];   // [3H][H]
  const float* bih[3];
  const float* bhh[3];
  float* h[3][2];        // quad-blocked [8][512][4]
  float* out_h;          // [B*T][H]
  int* leaf;             // [kPhases][8] stride-16 ints
  int* root;             // [kPhases] stride-16 ints
};

__device__ __forceinline__ void fma4(float a[4], float w, float4 v) {
  a[0] = fmaf(w, v.x, a[0]);
  a[1] = fmaf(w, v.y, a[1]);
  a[2] = fmaf(w, v.z, a[2]);
  a[3] = fmaf(w, v.w, a[3]);
}

template <int L>
__device__ __forceinline__ void layer_step(
    const GruParams& P, const float* __restrict__ wlds,
    int t, int rp, int wp, int q, int j, int jj, int ks,
    float bi0, float bi1, float bi2, float bh0, float bh1, float bh2) {
  constexpr int KA = (L == 0) ? kF : kH;
  const float* inA;
  if constexpr (L == 0)
    inA = P.xq + ((size_t)t * 8 + q) * (kF * 4);
  else
    inA = P.h[L - 1][rp] + q * (kH * 4);
  const float* inB = P.h[L][rp] + q * (kH * 4);
  const float* wa0 = &wlds[((L * 3 + 0) * 2 + jj) * 520];
  const float* wa1 = &wlds[((L * 3 + 1) * 2 + jj) * 520];
  const float* wa2 = &wlds[((L * 3 + 2) * 2 + jj) * 520];
  const float* wb0 = &wlds[9360 + ((L * 3 + 0) * 2 + jj) * 520];
  const float* wb1 = &wlds[9360 + ((L * 3 + 1) * 2 + jj) * 520];
  const float* wb2 = &wlds[9360 + ((L * 3 + 2) * 2 + jj) * 520];

  float aR[4]  = {0.f, 0.f, 0.f, 0.f};
  float aZ[4]  = {0.f, 0.f, 0.f, 0.f};
  float aNi[4] = {0.f, 0.f, 0.f, 0.f};
  float aNh[4] = {0.f, 0.f, 0.f, 0.f};

  // ---- segment A: w_ih . in ----
#pragma unroll
  for (int i = 0; i < 4; ++i) {
    const int k = 4 * ks + 128 * i;
    const float4 w0 = *reinterpret_cast<const float4*>(wa0 + k);
    const float4 w1 = *reinterpret_cast<const float4*>(wa1 + k);
    const float4 w2 = *reinterpret_cast<const float4*>(wa2 + k);
    const float4 v0 = *reinterpret_cast<const float4*>(inA + (size_t)(k + 0) * 4);
    const float4 v1 = *reinterpret_cast<const float4*>(inA + (size_t)(k + 1) * 4);
    const float4 v2 = *reinterpret_cast<const float4*>(inA + (size_t)(k + 2) * 4);
    const float4 v3 = *reinterpret_cast<const float4*>(inA + (size_t)(k + 3) * 4);
    fma4(aR, w0.x, v0);  fma4(aR, w0.y, v1);  fma4(aR, w0.z, v2);  fma4(aR, w0.w, v3);
    fma4(aZ, w1.x, v0);  fma4(aZ, w1.y, v1);  fma4(aZ, w1.z, v2);  fma4(aZ, w1.w, v3);
    fma4(aNi, w2.x, v0); fma4(aNi, w2.y, v1); fma4(aNi, w2.z, v2); fma4(aNi, w2.w, v3);
  }
  if constexpr (KA > 512) {
    if (ks == 0) {  // edge column k = 512
      const float4 v = *reinterpret_cast<const float4*>(inA + (size_t)512 * 4);
      fma4(aR,  wa0[512], v);
      fma4(aZ,  wa1[512], v);
      fma4(aNi, wa2[512], v);
    }
  }
  // ---- segment B: w_hh . h_old (R,Z merge into same accumulators) ----
#pragma unroll
  for (int i = 0; i < 4; ++i) {
    const int k = 4 * ks + 128 * i;
    const float4 w0 = *reinterpret_cast<const float4*>(wb0 + k);
    const float4 w1 = *reinterpret_cast<const float4*>(wb1 + k);
    const float4 w2 = *reinterpret_cast<const float4*>(wb2 + k);
    const float4 v0 = *reinterpret_cast<const float4*>(inB + (size_t)(k + 0) * 4);
    const float4 v1 = *reinterpret_cast<const float4*>(inB + (size_t)(k + 1) * 4);
    const float4 v2 = *reinterpret_cast<const float4*>(inB + (size_t)(k + 2) * 4);
    const float4 v3 = *reinterpret_cast<const float4*>(inB + (size_t)(k + 3) * 4);
    fma4(aR, w0.x, v0);  fma4(aR, w0.y, v1);  fma4(aR, w0.z, v2);  fma4(aR, w0.w, v3);
    fma4(aZ, w1.x, v0);  fma4(aZ, w1.y, v1);  fma4(aZ, w1.z, v2);  fma4(aZ, w1.w, v3);
    fma4(aNh, w2.x, v0); fma4(aNh, w2.y, v1); fma4(aNh, w2.z, v2); fma4(aNh, w2.w, v3);
  }
  // ---- butterfly all-reduce over the 32-lane half ----
#pragma unroll
  for (int m = 1; m <= 16; m <<= 1) {
#pragma unroll
    for (int c = 0; c < 4; ++c) {
      aR[c]  += __shfl_xor(aR[c],  m);
      aZ[c]  += __shfl_xor(aZ[c],  m);
      aNi[c] += __shfl_xor(aNi[c], m);
      aNh[c] += __shfl_xor(aNh[c], m);
    }
  }
  // ---- gate combine (precise transcendentals; round-1-proven numerics) ----
  if (ks < 4) {
    const int c = ks;
    const float r = 1.f / (1.f + expf(-(aR[c] + bi0 + bh0)));
    const float z = 1.f / (1.f + expf(-(aZ[c] + bi1 + bh1)));
    const float n = tanhf(aNi[c] + bi2 + r * (aNh[c] + bh2));
    const float ho = P.h[L][rp][(q * kH + j) * 4 + c];
    const float hn = (1.f - z) * n + z * ho;
    P.h[L][wp][(q * kH + j) * 4 + c] = hn;
    if constexpr (L == 2)
      P.out_h[((size_t)(q * 4 + c) * kT + t) * kH + j] = hn;
  }
}

__global__ __launch_bounds__(512) void gru_seq(GruParams P) {
  // LDS weights: segA rows [L][g][jj] stride 520, segB at +9360
  __shared__ float wlds[18720];  // 74.9 KB

  const int tid  = threadIdx.x;
  const int lane = tid & 63;
  const int u    = lane >> 5;
  const int ks   = lane & 31;
  const int wv   = tid >> 6;
  const int unit = wv * 2 + u;    // 0..15
  const int jj   = unit >> 3;     // 0..1
  const int q    = unit & 7;      // 0..7
  const int j    = blockIdx.x * 2 + jj;

  // ---- one-time weight preload into LDS ----
  for (int L = 0; L < 3; ++L) {
    const int KA = L ? kH : kF;
    for (int g = 0; g < 3; ++g)
#pragma unroll
      for (int j2 = 0; j2 < 2; ++j2) {
        const int row = ((L * 3 + g) * 2 + j2);
        const float* srcA = P.wih[L] + (size_t)(g * kH + blockIdx.x * 2 + j2) * KA;
        float* dstA = &wlds[row * 520];
        for (int k = tid; k < KA; k += 512) dstA[k] = srcA[k];
        const float* srcB = P.whh[L] + (size_t)(g * kH + blockIdx.x * 2 + j2) * kH;
        float* dstB = &wlds[9360 + row * 520];
        for (int k = tid; k < kH; k += 512) dstB[k] = srcB[k];
      }
  }
  // per-thread biases for this thread's j (constant-indexed after unroll)
  float bI[3][3], bH[3][3];
#pragma unroll
  for (int L = 0; L < 3; ++L)
#pragma unroll
    for (int g = 0; g < 3; ++g) {
      bI[L][g] = P.bih[L][g * kH + j];
      bH[L][g] = P.bhh[L][g * kH + j];
    }
  __syncthreads();

  for (int p = 0; p < kPhases; ++p) {
    const int wp = p & 1;
    const int rp = wp ^ 1;
    if (p < kT)
      layer_step<0>(P, wlds, p, rp, wp, q, j, jj, ks,
                    bI[0][0], bI[0][1], bI[0][2], bH[0][0], bH[0][1], bH[0][2]);
    if (p >= 1 && p <= kT)
      layer_step<1>(P, wlds, p - 1, rp, wp, q, j, jj, ks,
                    bI[1][0], bI[1][1], bI[1][2], bH[1][0], bH[1][1], bH[1][2]);
    if (p >= 2)
      layer_step<2>(P, wlds, p - 2, rp, wp, q, j, jj, ks,
                    bI[2][0], bI[2][1], bI[2][2], bH[2][0], bH[2][1], bH[2][2]);

    // ---- two-level grid barrier (fresh counters per phase) ----
    __syncthreads();
    if (tid == 0) {
      __threadfence();  // release this block's h writes (flush to coherent pt)
      const int g = blockIdx.x & 7;
      const int n = __hip_atomic_fetch_add(&P.leaf[(p * 8 + g) * 16], 1,
                                           __ATOMIC_ACQ_REL, __HIP_MEMORY_SCOPE_AGENT);
      if (n == 31)
        __hip_atomic_fetch_add(&P.root[p * 16], 1,
                               __ATOMIC_ACQ_REL, __HIP_MEMORY_SCOPE_AGENT);
      while (__hip_atomic_load(&P.root[p * 16], __ATOMIC_RELAXED,
                               __HIP_MEMORY_SCOPE_AGENT) < 8)
        __builtin_amdgcn_s_sleep(1);
      __threadfence();  // acquire side: one L1/L2 invalidate for the block
    }
    __syncthreads();
  }
}

// ---------------------------------------------------------------------------
// Kernel 3: fused head (unchanged; proven round 1).
// ---------------------------------------------------------------------------
__global__ __launch_bounds__(256) void out_mask(
    const float* __restrict__ A,   // out_h [B*T][H]
    const float* __restrict__ w1, const float* __restrict__ bl1,
    const float* __restrict__ w2, const float* __restrict__ bl2,
    const float* __restrict__ x,   // [B*T][F]
    float* __restrict__ o1, float* __restrict__ o2) {
  __shared__ float As[16][68], W1s[16][68], W2s[16][68];
  const int tid = threadIdx.x;
  const int n0 = blockIdx.x * 64;
  const int m0 = blockIdx.y * 64;
  const int tn = tid & 15, tm = tid >> 4;
  const int lr = tid >> 2;
  const int lk = (tid & 3) * 4;

  float ac1[4][4], ac2[4][4];
#pragma unroll
  for (int mm = 0; mm < 4; ++mm)
#pragma unroll
    for (int nn = 0; nn < 4; ++nn) { ac1[mm][nn] = 0.f; ac2[mm][nn] = 0.f; }

  for (int k0 = 0; k0 < kH; k0 += 16) {
    const float4 av = *reinterpret_cast<const float4*>(A + (size_t)(m0 + lr) * kH + k0 + lk);
    const int fA = n0 + lr;
    float4 wv1 = make_float4(0.f, 0.f, 0.f, 0.f);
    float4 wv2 = make_float4(0.f, 0.f, 0.f, 0.f);
    if (fA < kF) {
      wv1 = *reinterpret_cast<const float4*>(w1 + (size_t)fA * kH + k0 + lk);
      wv2 = *reinterpret_cast<const float4*>(w2 + (size_t)fA * kH + k0 + lk);
    }
    __syncthreads();
    As[lk + 0][lr] = av.x;  As[lk + 1][lr] = av.y;  As[lk + 2][lr] = av.z;  As[lk + 3][lr] = av.w;
    W1s[lk + 0][lr] = wv1.x; W1s[lk + 1][lr] = wv1.y; W1s[lk + 2][lr] = wv1.z; W1s[lk + 3][lr] = wv1.w;
    W2s[lk + 0][lr] = wv2.x; W2s[lk + 1][lr] = wv2.y; W2s[lk + 2][lr] = wv2.z; W2s[lk + 3][lr] = wv2.w;
    __syncthreads();
#pragma unroll
    for (int kk = 0; kk < 16; ++kk) {
      const float4 a = *reinterpret_cast<const float4*>(&As[kk][tm * 4]);
      const float4 uu4 = *reinterpret_cast<const float4*>(&W1s[kk][tn * 4]);
      const float4 vv4 = *reinterpret_cast<const float4*>(&W2s[kk][tn * 4]);
      const float aa[4] = {a.x, a.y, a.z, a.w};
      const float uu[4] = {uu4.x, uu4.y, uu4.z, uu4.w};
      const float vv[4] = {vv4.x, vv4.y, vv4.z, vv4.w};
#pragma unroll
      for (int mm = 0; mm < 4; ++mm)
#pragma unroll
        for (int nn = 0; nn < 4; ++nn) {
          ac1[mm][nn] += aa[mm] * uu[nn];
          ac2[mm][nn] += aa[mm] * vv[nn];
        }
    }
  }
#pragma unroll
  for (int mm = 0; mm < 4; ++mm) {
    const int row = m0 + tm * 4 + mm;
#pragma unroll
    for (int nn = 0; nn < 4; ++nn) {
      const int f = n0 + tn * 4 + nn;
      if (f < kF) {
        const float s1 = fmaxf(ac1[mm][nn] + bl1[f], 0.f);
        const float s2 = fmaxf(ac2[mm][nn] + bl2[f], 0.f);
        const float inv = 1.f / (s1 + s2 + 1e-16f);
        const float xv = x[(size_t)row * kF + f];
        o1[(size_t)row * kF + f] = s1 * inv * xv;
        o2[(size_t)row * kF + f] = s2 * inv * xv;
      }
    }
  }
}

// ---------------------------------------------------------------------------
extern "C" void kernel_launch(void* const* d_in, const int* in_sizes, int n_in,
                              void* d_out, int out_size, void* d_ws, size_t ws_size,
                              hipStream_t stream) {
  const float* x = (const float*)d_in[0];
  GruParams P;
  P.wih[0] = (const float*)d_in[1];  P.whh[0] = (const float*)d_in[2];
  P.bih[0] = (const float*)d_in[3];  P.bhh[0] = (const float*)d_in[4];
  P.wih[1] = (const float*)d_in[5];  P.whh[1] = (const float*)d_in[6];
  P.bih[1] = (const float*)d_in[7];  P.bhh[1] = (const float*)d_in[8];
  P.wih[2] = (const float*)d_in[9];  P.whh[2] = (const float*)d_in[10];
  P.bih[2] = (const float*)d_in[11]; P.bhh[2] = (const float*)d_in[12];
  const float* w_l1 = (const float*)d_in[13];
  const float* b_l1 = (const float*)d_in[14];
  const float* w_l2 = (const float*)d_in[15];
  const float* b_l2 = (const float*)d_in[16];

  // ws layout: counters (root[kPhases]*16 | leaf[kPhases][8]*16 ints),
  //            then 6 quad-blocked h buffers, then out_h.
  int* root = (int*)d_ws;
  int* leaf = root + kPhases * 16;
  int* cnt_end = leaf + kPhases * 8 * 16;
  float* ws = (float*)cnt_end;
  for (int l = 0; l < 3; ++l)
    for (int pp = 0; pp < 2; ++pp) {
      P.h[l][pp] = ws;
      ws += kH * kB;
    }
  float* out_h = ws;                                     // [B*T][H]
  P.root = root;
  P.leaf = leaf;
  P.out_h = out_h;

  // xq lives in the o1 half of d_out (dead until out_mask overwrites it):
  // [T][8][513][4] = 8,404,992 floats = exactly o1's size.
  float* o1 = (float*)d_out;
  float* o2 = o1 + (size_t)kB * kT * kF;
  float* xq = o1;
  P.xq = xq;

  // zero counters + h buffers (contiguous at ws start)
  const size_t zero_bytes = (size_t)(kPhases * 16 + kPhases * 8 * 16) * sizeof(int)
                          + (size_t)6 * kH * kB * sizeof(float);
  hipMemsetAsync(d_ws, 0, zero_bytes, stream);

  transpose_x<<<dim3(17, kT), 256, 0, stream>>>(x, xq);

  void* args[] = { (void*)&P };
  hipLaunchCooperativeKernel((void*)gru_seq, dim3(256), dim3(512), args, 0u, stream);

  out_mask<<<dim3(9, 256), 256, 0, stream>>>(out_h, w_l1, b_l1, w_l2, b_l2, x, o1, o2);
}

// Round 6
// 13230.968 us; speedup vs baseline: 1.7834x; 1.1423x over previous
//
#include <hip/hip_runtime.h>
#include <cstddef>

// Problem dims
constexpr int kB = 32;    // batch
constexpr int kT = 512;   // time steps
constexpr int kF = 513;   // input features
constexpr int kH = 512;   // hidden
constexpr int kPhases = kT + 2;  // skewed schedule

// ---------------------------------------------------------------------------
// Kernel 1: transpose x [B][T][F] -> xq [T][8][F][4]  (quad-blocked batch)
// ---------------------------------------------------------------------------
__global__ __launch_bounds__(256) void transpose_x(const float* __restrict__ x,
                                                   float* __restrict__ xq) {
  __shared__ float s[32][33];
  const int f0 = blockIdx.x * 32;
  const int t  = blockIdx.y;
  const int i  = threadIdx.x;
  const int lo = i & 31;
  const int g8 = i >> 5;  // 0..7
#pragma unroll
  for (int qq = 0; qq < 4; ++qq) {
    const int b = g8 * 4 + qq;
    const int f = f0 + lo;
    float v = 0.f;
    if (f < kF) v = x[((size_t)b * kT + t) * kF + f];
    s[b][lo] = v;
  }
  __syncthreads();
  const int r  = lo & 3;
  const int fl = lo >> 2;  // 0..7
#pragma unroll
  for (int it = 0; it < 4; ++it) {
    const int f = f0 + fl + 8 * it;
    if (f < kF)
      xq[((size_t)(t * 8 + g8) * kF + f) * 4 + r] = s[g8 * 4 + r][fl + 8 * it];
  }
}

// ---------------------------------------------------------------------------
// Kernel 2: persistent GRU. Math is BIT-EXACT round 3 (the passing kernel):
// per (column j, batch b, gate): lane ks in [0,32) accumulates quads
// k = 4*ks + 128*i (i=0..3, fma4 chains), L0 edge k=512 on ks==0 after segA,
// segB chained into the same accumulators, butterfly m=1..16, identical
// transcendental expressions. Only the WORK MAPPING changed:
//   192 blocks = 3 layers x 64 col-groups (8 cols each, weights LDS-resident)
//   512 threads = 16 units (32-lane half-waves): unit = (q, col-half);
//   each unit does 4 columns sequentially REUSING register-held inputs
//   (inA/inB loaded once -> ~128 KB unique post-fence reads per block/phase).
// Barrier: round-3-proven two-level fence barrier (threadfence = agent
// fence emits L2 writeback/invalidate on gfx950; rounds 1/3 validate it).
// ---------------------------------------------------------------------------
struct GruParams {
  const float* xq;       // [T][8][513][4]
  const float* wih[3];   // [3H][KA]
  const float* whh[3];   // [3H][H]
  const float* bih[3];
  const float* bhh[3];
  float* h[3][2];        // quad-blocked [8][512][4]
  float* out_h;          // [B*T][H]
  int* leaf;             // [kPhases][8] stride-16 ints
  int* root;             // [kPhases] stride-16 ints
};

__device__ __forceinline__ void fma4(float a[4], float w, float4 v) {
  a[0] = fmaf(w, v.x, a[0]);
  a[1] = fmaf(w, v.y, a[1]);
  a[2] = fmaf(w, v.z, a[2]);
  a[3] = fmaf(w, v.w, a[3]);
}

// branchless a[s] for s in 0..3 (exact select; no value change)
__device__ __forceinline__ float pick4(const float a[4], int s) {
  const float lo = (s & 1) ? a[1] : a[0];
  const float hi = (s & 1) ? a[3] : a[2];
  return (s & 2) ? hi : lo;
}

__global__ __launch_bounds__(512, 2) void gru_seq(GruParams P) {
  // weights: segA rows (g*8+c)*520, segB at +12480; biases at 24960 (48)
  __shared__ float wlds[25008];  // 100.0 KB

  const int tid = threadIdx.x;
  const int ks  = tid & 31;        // lane k-slice (round-3 semantics)
  const int unit = tid >> 5;       // 0..15 half-wave units
  const int q   = unit & 7;        // batch quad
  const int ch  = unit >> 3;       // column half (0..1) -> cols ch*4..ch*4+3
  const int Lb  = blockIdx.x >> 6; // this block's layer 0..2
  const int jc0 = (blockIdx.x & 63) * 8;

  // ---- one-time weight + bias preload into LDS (this layer, 8 columns) ----
  {
    const float* wihL = P.wih[Lb];
    const float* whhL = P.whh[Lb];
    const int KA = (Lb == 0) ? kF : kH;
    for (int g = 0; g < 3; ++g)
      for (int c = 0; c < 8; ++c) {
        const int row = g * 8 + c;
        const float* sA = wihL + (size_t)(g * kH + jc0 + c) * KA;
        float* dA = &wlds[row * 520];
        for (int k = tid; k < KA; k += 512) dA[k] = sA[k];
        const float* sB = whhL + (size_t)(g * kH + jc0 + c) * kH;
        float* dB = &wlds[12480 + row * 520];
        for (int k = tid; k < kH; k += 512) dB[k] = sB[k];
      }
    if (tid < 48) {
      const int s2 = tid / 24;          // 0 = ih, 1 = hh
      const int g  = (tid % 24) / 8;
      const int c  = tid & 7;
      const float* src = s2 ? P.bhh[Lb] : P.bih[Lb];
      wlds[24960 + tid] = src[g * kH + jc0 + c];
    }
  }
  __syncthreads();

  for (int p = 0; p < kPhases; ++p) {
    const int wp = p & 1;
    const int rp = wp ^ 1;
    const int t = p - Lb;
    if (t >= 0 && t < kT) {
      const float* inA = Lb ? (P.h[Lb - 1][rp] + q * (kH * 4))
                            : (P.xq + ((size_t)t * 8 + q) * (kF * 4));
      const float* inB = P.h[Lb][rp] + q * (kH * 4);

      // ---- load this lane's input quads ONCE (reused across 4 columns) ----
      float4 vA[4][4], vB[4][4];
#pragma unroll
      for (int i = 0; i < 4; ++i) {
        const int k = 4 * ks + 128 * i;
#pragma unroll
        for (int m = 0; m < 4; ++m) {
          vA[i][m] = *reinterpret_cast<const float4*>(inA + (size_t)(k + m) * 4);
          vB[i][m] = *reinterpret_cast<const float4*>(inB + (size_t)(k + m) * 4);
        }
      }
      float4 vE = make_float4(0.f, 0.f, 0.f, 0.f);
      if (Lb == 0 && ks == 0)
        vE = *reinterpret_cast<const float4*>(inA + (size_t)512 * 4);

      // ---- 4 columns sequentially; per-column math is bit-exact round 3 ----
#pragma unroll 1
      for (int cc = 0; cc < 4; ++cc) {
        const int col = ch * 4 + cc;     // local column 0..7
        const int jg  = jc0 + col;       // global column
        const float* wa0 = &wlds[(0 * 8 + col) * 520];
        const float* wa1 = &wlds[(1 * 8 + col) * 520];
        const float* wa2 = &wlds[(2 * 8 + col) * 520];
        const float* wb0 = &wlds[12480 + (0 * 8 + col) * 520];
        const float* wb1 = &wlds[12480 + (1 * 8 + col) * 520];
        const float* wb2 = &wlds[12480 + (2 * 8 + col) * 520];

        float aR[4]  = {0.f, 0.f, 0.f, 0.f};
        float aZ[4]  = {0.f, 0.f, 0.f, 0.f};
        float aNi[4] = {0.f, 0.f, 0.f, 0.f};
        float aNh[4] = {0.f, 0.f, 0.f, 0.f};

        // segment A: w_ih . in
#pragma unroll
        for (int i = 0; i < 4; ++i) {
          const int k = 4 * ks + 128 * i;
          const float4 w0 = *reinterpret_cast<const float4*>(wa0 + k);
          const float4 w1 = *reinterpret_cast<const float4*>(wa1 + k);
          const float4 w2 = *reinterpret_cast<const float4*>(wa2 + k);
          fma4(aR, w0.x, vA[i][0]);  fma4(aR, w0.y, vA[i][1]);
          fma4(aR, w0.z, vA[i][2]);  fma4(aR, w0.w, vA[i][3]);
          fma4(aZ, w1.x, vA[i][0]);  fma4(aZ, w1.y, vA[i][1]);
          fma4(aZ, w1.z, vA[i][2]);  fma4(aZ, w1.w, vA[i][3]);
          fma4(aNi, w2.x, vA[i][0]); fma4(aNi, w2.y, vA[i][1]);
          fma4(aNi, w2.z, vA[i][2]); fma4(aNi, w2.w, vA[i][3]);
        }
        if (Lb == 0 && ks == 0) {  // edge column k = 512 (after segA, as r3)
          fma4(aR,  wa0[512], vE);
          fma4(aZ,  wa1[512], vE);
          fma4(aNi, wa2[512], vE);
        }
        // segment B: w_hh . h_old (R,Z chain into same accumulators)
#pragma unroll
        for (int i = 0; i < 4; ++i) {
          const int k = 4 * ks + 128 * i;
          const float4 w0 = *reinterpret_cast<const float4*>(wb0 + k);
          const float4 w1 = *reinterpret_cast<const float4*>(wb1 + k);
          const float4 w2 = *reinterpret_cast<const float4*>(wb2 + k);
          fma4(aR, w0.x, vB[i][0]);  fma4(aR, w0.y, vB[i][1]);
          fma4(aR, w0.z, vB[i][2]);  fma4(aR, w0.w, vB[i][3]);
          fma4(aZ, w1.x, vB[i][0]);  fma4(aZ, w1.y, vB[i][1]);
          fma4(aZ, w1.z, vB[i][2]);  fma4(aZ, w1.w, vB[i][3]);
          fma4(aNh, w2.x, vB[i][0]); fma4(aNh, w2.y, vB[i][1]);
          fma4(aNh, w2.z, vB[i][2]); fma4(aNh, w2.w, vB[i][3]);
        }
        // butterfly all-reduce over the 32-lane half (exact round-3 order)
#pragma unroll
        for (int m = 1; m <= 16; m <<= 1) {
#pragma unroll
          for (int c2 = 0; c2 < 4; ++c2) {
            aR[c2]  += __shfl_xor(aR[c2],  m);
            aZ[c2]  += __shfl_xor(aZ[c2],  m);
            aNi[c2] += __shfl_xor(aNi[c2], m);
            aNh[c2] += __shfl_xor(aNh[c2], m);
          }
        }
        // gate combine: lanes ks<4 handle batch b = q*4 + ks
        if (ks < 4) {
          const float bi0 = wlds[24960 + 0 * 8 + col];
          const float bi1 = wlds[24960 + 1 * 8 + col];
          const float bi2 = wlds[24960 + 2 * 8 + col];
          const float bh0 = wlds[24960 + 24 + 0 * 8 + col];
          const float bh1 = wlds[24960 + 24 + 1 * 8 + col];
          const float bh2 = wlds[24960 + 24 + 2 * 8 + col];
          const float sR  = pick4(aR, ks);
          const float sZ  = pick4(aZ, ks);
          const float sNi = pick4(aNi, ks);
          const float sNh = pick4(aNh, ks);
          const float r = 1.f / (1.f + expf(-(sR + bi0 + bh0)));
          const float z = 1.f / (1.f + expf(-(sZ + bi1 + bh1)));
          const float n = tanhf(sNi + bi2 + r * (sNh + bh2));
          const float ho = inB[jg * 4 + ks];
          const float hn = (1.f - z) * n + z * ho;
          P.h[Lb][wp][(q * kH + jg) * 4 + ks] = hn;
          if (Lb == 2)
            P.out_h[((size_t)(q * 4 + ks) * kT + t) * kH + jg] = hn;
        }
      }
    }
    // ---- two-level grid barrier (round-3-proven, fresh counters) ----
    __syncthreads();
    if (tid == 0) {
      __threadfence();  // release: agent fence -> L2 writeback on gfx950
      const int g = blockIdx.x & 7;
      const int n = __hip_atomic_fetch_add(&P.leaf[(p * 8 + g) * 16], 1,
                                           __ATOMIC_ACQ_REL, __HIP_MEMORY_SCOPE_AGENT);
      if (n == 23)  // 24 blocks per leaf group (192 / 8)
        __hip_atomic_fetch_add(&P.root[p * 16], 1,
                               __ATOMIC_ACQ_REL, __HIP_MEMORY_SCOPE_AGENT);
      while (__hip_atomic_load(&P.root[p * 16], __ATOMIC_RELAXED,
                               __HIP_MEMORY_SCOPE_AGENT) < 8)
        __builtin_amdgcn_s_sleep(1);
      __threadfence();  // acquire: invalidate L1/L2 once per block per phase
    }
    __syncthreads();
  }
}

// ---------------------------------------------------------------------------
// Kernel 3: fused head (unchanged; bit-identical to rounds 1/3).
// ---------------------------------------------------------------------------
__global__ __launch_bounds__(256) void out_mask(
    const float* __restrict__ A,   // out_h [B*T][H]
    const float* __restrict__ w1, const float* __restrict__ bl1,
    const float* __restrict__ w2, const float* __restrict__ bl2,
    const float* __restrict__ x,   // [B*T][F]
    float* __restrict__ o1, float* __restrict__ o2) {
  __shared__ float As[16][68], W1s[16][68], W2s[16][68];
  const int tid = threadIdx.x;
  const int n0 = blockIdx.x * 64;
  const int m0 = blockIdx.y * 64;
  const int tn = tid & 15, tm = tid >> 4;
  const int lr = tid >> 2;
  const int lk = (tid & 3) * 4;

  float ac1[4][4], ac2[4][4];
#pragma unroll
  for (int mm = 0; mm < 4; ++mm)
#pragma unroll
    for (int nn = 0; nn < 4; ++nn) { ac1[mm][nn] = 0.f; ac2[mm][nn] = 0.f; }

  for (int k0 = 0; k0 < kH; k0 += 16) {
    const float4 av = *reinterpret_cast<const float4*>(A + (size_t)(m0 + lr) * kH + k0 + lk);
    const int fA = n0 + lr;
    float4 wv1 = make_float4(0.f, 0.f, 0.f, 0.f);
    float4 wv2 = make_float4(0.f, 0.f, 0.f, 0.f);
    if (fA < kF) {
      wv1 = *reinterpret_cast<const float4*>(w1 + (size_t)fA * kH + k0 + lk);
      wv2 = *reinterpret_cast<const float4*>(w2 + (size_t)fA * kH + k0 + lk);
    }
    __syncthreads();
    As[lk + 0][lr] = av.x;  As[lk + 1][lr] = av.y;  As[lk + 2][lr] = av.z;  As[lk + 3][lr] = av.w;
    W1s[lk + 0][lr] = wv1.x; W1s[lk + 1][lr] = wv1.y; W1s[lk + 2][lr] = wv1.z; W1s[lk + 3][lr] = wv1.w;
    W2s[lk + 0][lr] = wv2.x; W2s[lk + 1][lr] = wv2.y; W2s[lk + 2][lr] = wv2.z; W2s[lk + 3][lr] = wv2.w;
    __syncthreads();
#pragma unroll
    for (int kk = 0; kk < 16; ++kk) {
      const float4 a = *reinterpret_cast<const float4*>(&As[kk][tm * 4]);
      const float4 uu4 = *reinterpret_cast<const float4*>(&W1s[kk][tn * 4]);
      const float4 vv4 = *reinterpret_cast<const float4*>(&W2s[kk][tn * 4]);
      const float aa[4] = {a.x, a.y, a.z, a.w};
      const float uu[4] = {uu4.x, uu4.y, uu4.z, uu4.w};
      const float vv[4] = {vv4.x, vv4.y, vv4.z, vv4.w};
#pragma unroll
      for (int mm = 0; mm < 4; ++mm)
#pragma unroll
        for (int nn = 0; nn < 4; ++nn) {
          ac1[mm][nn] += aa[mm] * uu[nn];
          ac2[mm][nn] += aa[mm] * vv[nn];
        }
    }
  }
#pragma unroll
  for (int mm = 0; mm < 4; ++mm) {
    const int row = m0 + tm * 4 + mm;
#pragma unroll
    for (int nn = 0; nn < 4; ++nn) {
      const int f = n0 + tn * 4 + nn;
      if (f < kF) {
        const float s1 = fmaxf(ac1[mm][nn] + bl1[f], 0.f);
        const float s2 = fmaxf(ac2[mm][nn] + bl2[f], 0.f);
        const float inv = 1.f / (s1 + s2 + 1e-16f);
        const float xv = x[(size_t)row * kF + f];
        o1[(size_t)row * kF + f] = s1 * inv * xv;
        o2[(size_t)row * kF + f] = s2 * inv * xv;
      }
    }
  }
}

// ---------------------------------------------------------------------------
extern "C" void kernel_launch(void* const* d_in, const int* in_sizes, int n_in,
                              void* d_out, int out_size, void* d_ws, size_t ws_size,
                              hipStream_t stream) {
  const float* x = (const float*)d_in[0];
  GruParams P;
  P.wih[0] = (const float*)d_in[1];  P.whh[0] = (const float*)d_in[2];
  P.bih[0] = (const float*)d_in[3];  P.bhh[0] = (const float*)d_in[4];
  P.wih[1] = (const float*)d_in[5];  P.whh[1] = (const float*)d_in[6];
  P.bih[1] = (const float*)d_in[7];  P.bhh[1] = (const float*)d_in[8];
  P.wih[2] = (const float*)d_in[9];  P.whh[2] = (const float*)d_in[10];
  P.bih[2] = (const float*)d_in[11]; P.bhh[2] = (const float*)d_in[12];
  const float* w_l1 = (const float*)d_in[13];
  const float* b_l1 = (const float*)d_in[14];
  const float* w_l2 = (const float*)d_in[15];
  const float* b_l2 = (const float*)d_in[16];

  // ws layout: counters (root[kPhases]*16 | leaf[kPhases][8]*16 ints),
  //            then 6 quad-blocked h buffers, then out_h.
  int* root = (int*)d_ws;
  int* leaf = root + kPhases * 16;
  int* cnt_end = leaf + kPhases * 8 * 16;
  float* ws = (float*)cnt_end;
  for (int l = 0; l < 3; ++l)
    for (int pp = 0; pp < 2; ++pp) {
      P.h[l][pp] = ws;
      ws += kH * kB;
    }
  float* out_h = ws;                                     // [B*T][H]
  P.root = root;
  P.leaf = leaf;
  P.out_h = out_h;

  // xq lives in the o1 half of d_out (dead until out_mask overwrites it):
  // [T][8][513][4] = 8,404,992 floats = exactly o1's size.
  float* o1 = (float*)d_out;
  float* o2 = o1 + (size_t)kB * kT * kF;
  float* xq = o1;
  P.xq = xq;

  // zero counters + h buffers (contiguous at ws start)
  const size_t zero_bytes = (size_t)(kPhases * 16 + kPhases * 8 * 16) * sizeof(int)
                          + (size_t)6 * kH * kB * sizeof(float);
  hipMemsetAsync(d_ws, 0, zero_bytes, stream);

  transpose_x<<<dim3(17, kT), 256, 0, stream>>>(x, xq);

  void* args[] = { (void*)&P };
  hipLaunchCooperativeKernel((void*)gru_seq, dim3(192), dim3(512), args, 0u, stream);

  out_mask<<<dim3(9, 256), 256, 0, stream>>>(out_h, w_l1, b_l1, w_l2, b_l2, x, o1, o2);
}

// Round 7
// 12869.513 us; speedup vs baseline: 1.8335x; 1.0281x over previous
//
#include <hip/hip_runtime.h>
#include <cstddef>

// Problem dims
constexpr int kB = 32;    // batch
constexpr int kT = 512;   // time steps
constexpr int kF = 513;   // input features
constexpr int kH = 512;   // hidden
constexpr int kPhases = kT + 2;  // skewed schedule

// ---------------------------------------------------------------------------
// Agent-coherent load/store helpers: relaxed atomics compile to global
// load/store with sc0/sc1 set -> always read/write the device coherence
// point, bypassing stale (non-cross-XCD-coherent) L1/L2 copies. This makes
// the h ping-pong exchange coherent BY CONSTRUCTION, so the grid barrier
// needs no buffer_wbl2/buffer_inv cache maintenance (the round-6 stall).
// ---------------------------------------------------------------------------
__device__ __forceinline__ float2 aload_f2(const float* p) {
  unsigned long long u = __hip_atomic_load(
      reinterpret_cast<const unsigned long long*>(p),
      __ATOMIC_RELAXED, __HIP_MEMORY_SCOPE_AGENT);
  float2 r;
  r.x = __uint_as_float((unsigned)(u & 0xffffffffull));
  r.y = __uint_as_float((unsigned)(u >> 32));
  return r;
}
__device__ __forceinline__ float4 aload_f4(const float* p) {
  const float2 a = aload_f2(p);
  const float2 b = aload_f2(p + 2);
  return make_float4(a.x, a.y, b.x, b.y);
}
__device__ __forceinline__ float aload_f(const float* p) {
  return __hip_atomic_load(const_cast<float*>(p), __ATOMIC_RELAXED,
                           __HIP_MEMORY_SCOPE_AGENT);
}
__device__ __forceinline__ void astore_f(float* p, float v) {
  __hip_atomic_store(p, v, __ATOMIC_RELAXED, __HIP_MEMORY_SCOPE_AGENT);
}

// ---------------------------------------------------------------------------
// Kernel 1: transpose x [B][T][F] -> xq [T][8][F][4]  (quad-blocked batch)
// ---------------------------------------------------------------------------
__global__ __launch_bounds__(256) void transpose_x(const float* __restrict__ x,
                                                   float* __restrict__ xq) {
  __shared__ float s[32][33];
  const int f0 = blockIdx.x * 32;
  const int t  = blockIdx.y;
  const int i  = threadIdx.x;
  const int lo = i & 31;
  const int g8 = i >> 5;  // 0..7
#pragma unroll
  for (int qq = 0; qq < 4; ++qq) {
    const int b = g8 * 4 + qq;
    const int f = f0 + lo;
    float v = 0.f;
    if (f < kF) v = x[((size_t)b * kT + t) * kF + f];
    s[b][lo] = v;
  }
  __syncthreads();
  const int r  = lo & 3;
  const int fl = lo >> 2;  // 0..7
#pragma unroll
  for (int it = 0; it < 4; ++it) {
    const int f = f0 + fl + 8 * it;
    if (f < kF)
      xq[((size_t)(t * 8 + g8) * kF + f) * 4 + r] = s[g8 * 4 + r][fl + 8 * it];
  }
}

// ---------------------------------------------------------------------------
// Kernel 2: persistent GRU. Math is BIT-EXACT rounds 3/6 (passing kernels).
// Mapping identical to round 6 (192 layer-specialized blocks, 8 cols each,
// weights+biases LDS-resident, 16 half-wave units x 4 sequential columns,
// register-held inputs). Changes vs round 6, perf-only:
//   * h ping-pong loads/stores -> relaxed agent atomics (coherence point)
//   * grid barrier: NO __threadfence (no buffer_wbl2 / buffer_inv);
//     counter atomics relaxed. __syncthreads drains each wave's sc-stores
//     before tid0 increments the leaf counter -> ordering preserved.
// ---------------------------------------------------------------------------
struct GruParams {
  const float* xq;       // [T][8][513][4]
  const float* wih[3];   // [3H][KA]
  const float* whh[3];   // [3H][H]
  const float* bih[3];
  const float* bhh[3];
  float* h[3][2];        // quad-blocked [8][512][4]
  float* out_h;          // [B*T][H]
  int* leaf;             // [kPhases][8] stride-16 ints
  int* root;             // [kPhases] stride-16 ints
};

__device__ __forceinline__ void fma4(float a[4], float w, float4 v) {
  a[0] = fmaf(w, v.x, a[0]);
  a[1] = fmaf(w, v.y, a[1]);
  a[2] = fmaf(w, v.z, a[2]);
  a[3] = fmaf(w, v.w, a[3]);
}

// branchless a[s] for s in 0..3 (exact select; no value change)
__device__ __forceinline__ float pick4(const float a[4], int s) {
  const float lo = (s & 1) ? a[1] : a[0];
  const float hi = (s & 1) ? a[3] : a[2];
  return (s & 2) ? hi : lo;
}

__global__ __launch_bounds__(512, 2) void gru_seq(GruParams P) {
  // weights: segA rows (g*8+c)*520, segB at +12480; biases at 24960 (48)
  __shared__ float wlds[25008];  // 100.0 KB

  const int tid = threadIdx.x;
  const int ks  = tid & 31;        // lane k-slice (round-3 semantics)
  const int unit = tid >> 5;       // 0..15 half-wave units
  const int q   = unit & 7;        // batch quad
  const int ch  = unit >> 3;       // column half (0..1) -> cols ch*4..ch*4+3
  const int Lb  = blockIdx.x >> 6; // this block's layer 0..2
  const int jc0 = (blockIdx.x & 63) * 8;

  // ---- one-time weight + bias preload into LDS (this layer, 8 columns) ----
  {
    const float* wihL = P.wih[Lb];
    const float* whhL = P.whh[Lb];
    const int KA = (Lb == 0) ? kF : kH;
    for (int g = 0; g < 3; ++g)
      for (int c = 0; c < 8; ++c) {
        const int row = g * 8 + c;
        const float* sA = wihL + (size_t)(g * kH + jc0 + c) * KA;
        float* dA = &wlds[row * 520];
        for (int k = tid; k < KA; k += 512) dA[k] = sA[k];
        const float* sB = whhL + (size_t)(g * kH + jc0 + c) * kH;
        float* dB = &wlds[12480 + row * 520];
        for (int k = tid; k < kH; k += 512) dB[k] = sB[k];
      }
    if (tid < 48) {
      const int s2 = tid / 24;          // 0 = ih, 1 = hh
      const int g  = (tid % 24) / 8;
      const int c  = tid & 7;
      const float* src = s2 ? P.bhh[Lb] : P.bih[Lb];
      wlds[24960 + tid] = src[g * kH + jc0 + c];
    }
  }
  __syncthreads();

  for (int p = 0; p < kPhases; ++p) {
    const int wp = p & 1;
    const int rp = wp ^ 1;
    const int t = p - Lb;
    if (t >= 0 && t < kT) {
      const float* inB = P.h[Lb][rp] + q * (kH * 4);

      // ---- load this lane's input quads ONCE (reused across 4 columns) ----
      // Values are identical to round 6; only the load instruction differs
      // (agent-coherent sc loads for cross-block h data).
      float4 vA[4][4], vB[4][4];
      if (Lb == 0) {
        const float* inA = P.xq + ((size_t)t * 8 + q) * (kF * 4);
#pragma unroll
        for (int i = 0; i < 4; ++i) {
          const int k = 4 * ks + 128 * i;
#pragma unroll
          for (int m = 0; m < 4; ++m) {
            vA[i][m] = *reinterpret_cast<const float4*>(inA + (size_t)(k + m) * 4);
            vB[i][m] = aload_f4(inB + (size_t)(k + m) * 4);
          }
        }
      } else {
        const float* inA = P.h[Lb - 1][rp] + q * (kH * 4);
#pragma unroll
        for (int i = 0; i < 4; ++i) {
          const int k = 4 * ks + 128 * i;
#pragma unroll
          for (int m = 0; m < 4; ++m) {
            vA[i][m] = aload_f4(inA + (size_t)(k + m) * 4);
            vB[i][m] = aload_f4(inB + (size_t)(k + m) * 4);
          }
        }
      }
      float4 vE = make_float4(0.f, 0.f, 0.f, 0.f);
      if (Lb == 0 && ks == 0)
        vE = *reinterpret_cast<const float4*>(P.xq + ((size_t)t * 8 + q) * (kF * 4)
                                              + (size_t)512 * 4);

      // ---- 4 columns sequentially; per-column math bit-exact round 3/6 ----
#pragma unroll 1
      for (int cc = 0; cc < 4; ++cc) {
        const int col = ch * 4 + cc;     // local column 0..7
        const int jg  = jc0 + col;       // global column
        const float* wa0 = &wlds[(0 * 8 + col) * 520];
        const float* wa1 = &wlds[(1 * 8 + col) * 520];
        const float* wa2 = &wlds[(2 * 8 + col) * 520];
        const float* wb0 = &wlds[12480 + (0 * 8 + col) * 520];
        const float* wb1 = &wlds[12480 + (1 * 8 + col) * 520];
        const float* wb2 = &wlds[12480 + (2 * 8 + col) * 520];

        float aR[4]  = {0.f, 0.f, 0.f, 0.f};
        float aZ[4]  = {0.f, 0.f, 0.f, 0.f};
        float aNi[4] = {0.f, 0.f, 0.f, 0.f};
        float aNh[4] = {0.f, 0.f, 0.f, 0.f};

        // segment A: w_ih . in
#pragma unroll
        for (int i = 0; i < 4; ++i) {
          const int k = 4 * ks + 128 * i;
          const float4 w0 = *reinterpret_cast<const float4*>(wa0 + k);
          const float4 w1 = *reinterpret_cast<const float4*>(wa1 + k);
          const float4 w2 = *reinterpret_cast<const float4*>(wa2 + k);
          fma4(aR, w0.x, vA[i][0]);  fma4(aR, w0.y, vA[i][1]);
          fma4(aR, w0.z, vA[i][2]);  fma4(aR, w0.w, vA[i][3]);
          fma4(aZ, w1.x, vA[i][0]);  fma4(aZ, w1.y, vA[i][1]);
          fma4(aZ, w1.z, vA[i][2]);  fma4(aZ, w1.w, vA[i][3]);
          fma4(aNi, w2.x, vA[i][0]); fma4(aNi, w2.y, vA[i][1]);
          fma4(aNi, w2.z, vA[i][2]); fma4(aNi, w2.w, vA[i][3]);
        }
        if (Lb == 0 && ks == 0) {  // edge column k = 512 (after segA)
          fma4(aR,  wa0[512], vE);
          fma4(aZ,  wa1[512], vE);
          fma4(aNi, wa2[512], vE);
        }
        // segment B: w_hh . h_old (R,Z chain into same accumulators)
#pragma unroll
        for (int i = 0; i < 4; ++i) {
          const int k = 4 * ks + 128 * i;
          const float4 w0 = *reinterpret_cast<const float4*>(wb0 + k);
          const float4 w1 = *reinterpret_cast<const float4*>(wb1 + k);
          const float4 w2 = *reinterpret_cast<const float4*>(wb2 + k);
          fma4(aR, w0.x, vB[i][0]);  fma4(aR, w0.y, vB[i][1]);
          fma4(aR, w0.z, vB[i][2]);  fma4(aR, w0.w, vB[i][3]);
          fma4(aZ, w1.x, vB[i][0]);  fma4(aZ, w1.y, vB[i][1]);
          fma4(aZ, w1.z, vB[i][2]);  fma4(aZ, w1.w, vB[i][3]);
          fma4(aNh, w2.x, vB[i][0]); fma4(aNh, w2.y, vB[i][1]);
          fma4(aNh, w2.z, vB[i][2]); fma4(aNh, w2.w, vB[i][3]);
        }
        // butterfly all-reduce over the 32-lane half (exact round-3 order)
#pragma unroll
        for (int m = 1; m <= 16; m <<= 1) {
#pragma unroll
          for (int c2 = 0; c2 < 4; ++c2) {
            aR[c2]  += __shfl_xor(aR[c2],  m);
            aZ[c2]  += __shfl_xor(aZ[c2],  m);
            aNi[c2] += __shfl_xor(aNi[c2], m);
            aNh[c2] += __shfl_xor(aNh[c2], m);
          }
        }
        // gate combine: lanes ks<4 handle batch b = q*4 + ks
        if (ks < 4) {
          const float bi0 = wlds[24960 + 0 * 8 + col];
          const float bi1 = wlds[24960 + 1 * 8 + col];
          const float bi2 = wlds[24960 + 2 * 8 + col];
          const float bh0 = wlds[24960 + 24 + 0 * 8 + col];
          const float bh1 = wlds[24960 + 24 + 1 * 8 + col];
          const float bh2 = wlds[24960 + 24 + 2 * 8 + col];
          const float sR  = pick4(aR, ks);
          const float sZ  = pick4(aZ, ks);
          const float sNi = pick4(aNi, ks);
          const float sNh = pick4(aNh, ks);
          const float r = 1.f / (1.f + expf(-(sR + bi0 + bh0)));
          const float z = 1.f / (1.f + expf(-(sZ + bi1 + bh1)));
          const float n = tanhf(sNi + bi2 + r * (sNh + bh2));
          const float ho = aload_f(inB + jg * 4 + ks);
          const float hn = (1.f - z) * n + z * ho;
          astore_f(&P.h[Lb][wp][(q * kH + jg) * 4 + ks], hn);
          if (Lb == 2)
            P.out_h[((size_t)(q * 4 + ks) * kT + t) * kH + jg] = hn;
        }
      }
    }
    // ---- two-level grid barrier, fence-free (fresh counters per phase).
    // __syncthreads drains every wave's sc-stores (vmcnt=0 -> at coherence
    // point) before tid0 counts this block as done; readers use sc-loads.
    __syncthreads();
    if (tid == 0) {
      const int g = blockIdx.x & 7;
      const int n = __hip_atomic_fetch_add(&P.leaf[(p * 8 + g) * 16], 1,
                                           __ATOMIC_RELAXED, __HIP_MEMORY_SCOPE_AGENT);
      if (n == 23)  // 24 blocks per leaf group (192 / 8)
        __hip_atomic_fetch_add(&P.root[p * 16], 1,
                               __ATOMIC_RELAXED, __HIP_MEMORY_SCOPE_AGENT);
      while (__hip_atomic_load(&P.root[p * 16], __ATOMIC_RELAXED,
                               __HIP_MEMORY_SCOPE_AGENT) < 8)
        __builtin_amdgcn_s_sleep(1);
    }
    __syncthreads();
  }
}

// ---------------------------------------------------------------------------
// Kernel 3: fused head (unchanged; bit-identical to rounds 1/3/6).
// ---------------------------------------------------------------------------
__global__ __launch_bounds__(256) void out_mask(
    const float* __restrict__ A,   // out_h [B*T][H]
    const float* __restrict__ w1, const float* __restrict__ bl1,
    const float* __restrict__ w2, const float* __restrict__ bl2,
    const float* __restrict__ x,   // [B*T][F]
    float* __restrict__ o1, float* __restrict__ o2) {
  __shared__ float As[16][68], W1s[16][68], W2s[16][68];
  const int tid = threadIdx.x;
  const int n0 = blockIdx.x * 64;
  const int m0 = blockIdx.y * 64;
  const int tn = tid & 15, tm = tid >> 4;
  const int lr = tid >> 2;
  const int lk = (tid & 3) * 4;

  float ac1[4][4], ac2[4][4];
#pragma unroll
  for (int mm = 0; mm < 4; ++mm)
#pragma unroll
    for (int nn = 0; nn < 4; ++nn) { ac1[mm][nn] = 0.f; ac2[mm][nn] = 0.f; }

  for (int k0 = 0; k0 < kH; k0 += 16) {
    const float4 av = *reinterpret_cast<const float4*>(A + (size_t)(m0 + lr) * kH + k0 + lk);
    const int fA = n0 + lr;
    float4 wv1 = make_float4(0.f, 0.f, 0.f, 0.f);
    float4 wv2 = make_float4(0.f, 0.f, 0.f, 0.f);
    if (fA < kF) {
      wv1 = *reinterpret_cast<const float4*>(w1 + (size_t)fA * kH + k0 + lk);
      wv2 = *reinterpret_cast<const float4*>(w2 + (size_t)fA * kH + k0 + lk);
    }
    __syncthreads();
    As[lk + 0][lr] = av.x;  As[lk + 1][lr] = av.y;  As[lk + 2][lr] = av.z;  As[lk + 3][lr] = av.w;
    W1s[lk + 0][lr] = wv1.x; W1s[lk + 1][lr] = wv1.y; W1s[lk + 2][lr] = wv1.z; W1s[lk + 3][lr] = wv1.w;
    W2s[lk + 0][lr] = wv2.x; W2s[lk + 1][lr] = wv2.y; W2s[lk + 2][lr] = wv2.z; W2s[lk + 3][lr] = wv2.w;
    __syncthreads();
#pragma unroll
    for (int kk = 0; kk < 16; ++kk) {
      const float4 a = *reinterpret_cast<const float4*>(&As[kk][tm * 4]);
      const float4 uu4 = *reinterpret_cast<const float4*>(&W1s[kk][tn * 4]);
      const float4 vv4 = *reinterpret_cast<const float4*>(&W2s[kk][tn * 4]);
      const float aa[4] = {a.x, a.y, a.z, a.w};
      const float uu[4] = {uu4.x, uu4.y, uu4.z, uu4.w};
      const float vv[4] = {vv4.x, vv4.y, vv4.z, vv4.w};
#pragma unroll
      for (int mm = 0; mm < 4; ++mm)
#pragma unroll
        for (int nn = 0; nn < 4; ++nn) {
          ac1[mm][nn] += aa[mm] * uu[nn];
          ac2[mm][nn] += aa[mm] * vv[nn];
        }
    }
  }
#pragma unroll
  for (int mm = 0; mm < 4; ++mm) {
    const int row = m0 + tm * 4 + mm;
#pragma unroll
    for (int nn = 0; nn < 4; ++nn) {
      const int f = n0 + tn * 4 + nn;
      if (f < kF) {
        const float s1 = fmaxf(ac1[mm][nn] + bl1[f], 0.f);
        const float s2 = fmaxf(ac2[mm][nn] + bl2[f], 0.f);
        const float inv = 1.f / (s1 + s2 + 1e-16f);
        const float xv = x[(size_t)row * kF + f];
        o1[(size_t)row * kF + f] = s1 * inv * xv;
        o2[(size_t)row * kF + f] = s2 * inv * xv;
      }
    }
  }
}

// ---------------------------------------------------------------------------
extern "C" void kernel_launch(void* const* d_in, const int* in_sizes, int n_in,
                              void* d_out, int out_size, void* d_ws, size_t ws_size,
                              hipStream_t stream) {
  const float* x = (const float*)d_in[0];
  GruParams P;
  P.wih[0] = (const float*)d_in[1];  P.whh[0] = (const float*)d_in[2];
  P.bih[0] = (const float*)d_in[3];  P.bhh[0] = (const float*)d_in[4];
  P.wih[1] = (const float*)d_in[5];  P.whh[1] = (const float*)d_in[6];
  P.bih[1] = (const float*)d_in[7];  P.bhh[1] = (const float*)d_in[8];
  P.wih[2] = (const float*)d_in[9];  P.whh[2] = (const float*)d_in[10];
  P.bih[2] = (const float*)d_in[11]; P.bhh[2] = (const float*)d_in[12];
  const float* w_l1 = (const float*)d_in[13];
  const float* b_l1 = (const float*)d_in[14];
  const float* w_l2 = (const float*)d_in[15];
  const float* b_l2 = (const float*)d_in[16];

  // ws layout: counters (root[kPhases]*16 | leaf[kPhases][8]*16 ints),
  //            then 6 quad-blocked h buffers, then out_h.
  int* root = (int*)d_ws;
  int* leaf = root + kPhases * 16;
  int* cnt_end = leaf + kPhases * 8 * 16;
  float* ws = (float*)cnt_end;
  for (int l = 0; l < 3; ++l)
    for (int pp = 0; pp < 2; ++pp) {
      P.h[l][pp] = ws;
      ws += kH * kB;
    }
  float* out_h = ws;                                     // [B*T][H]
  P.root = root;
  P.leaf = leaf;
  P.out_h = out_h;

  // xq lives in the o1 half of d_out (dead until out_mask overwrites it):
  // [T][8][513][4] = 8,404,992 floats = exactly o1's size.
  float* o1 = (float*)d_out;
  float* o2 = o1 + (size_t)kB * kT * kF;
  float* xq = o1;
  P.xq = xq;

  // zero counters + h buffers (contiguous at ws start)
  const size_t zero_bytes = (size_t)(kPhases * 16 + kPhases * 8 * 16) * sizeof(int)
                          + (size_t)6 * kH * kB * sizeof(float);
  hipMemsetAsync(d_ws, 0, zero_bytes, stream);

  transpose_x<<<dim3(17, kT), 256, 0, stream>>>(x, xq);

  void* args[] = { (void*)&P };
  hipLaunchCooperativeKernel((void*)gru_seq, dim3(192), dim3(512), args, 0u, stream);

  out_mask<<<dim3(9, 256), 256, 0, stream>>>(out_h, w_l1, b_l1, w_l2, b_l2, x, o1, o2);
}

// Round 8
// 12636.443 us; speedup vs baseline: 1.8674x; 1.0184x over previous
//
#include <hip/hip_runtime.h>
#include <cstddef>

// Problem dims
constexpr int kB = 32;    // batch
constexpr int kT = 512;   // time steps
constexpr int kF = 513;   // input features
constexpr int kH = 512;   // hidden
constexpr int kPhases = kT + 2;  // skewed schedule

// ---------------------------------------------------------------------------
// Agent-coherent load/store helpers (relaxed atomics -> sc0/sc1 global ops,
// served at the device coherence point; immune to stale per-XCD L2).
// ---------------------------------------------------------------------------
__device__ __forceinline__ float2 aload_f2(const float* p) {
  unsigned long long u = __hip_atomic_load(
      reinterpret_cast<const unsigned long long*>(p),
      __ATOMIC_RELAXED, __HIP_MEMORY_SCOPE_AGENT);
  float2 r;
  r.x = __uint_as_float((unsigned)(u & 0xffffffffull));
  r.y = __uint_as_float((unsigned)(u >> 32));
  return r;
}
__device__ __forceinline__ float4 aload_f4(const float* p) {
  const float2 a = aload_f2(p);
  const float2 b = aload_f2(p + 2);
  return make_float4(a.x, a.y, b.x, b.y);
}
__device__ __forceinline__ float aload_f(const float* p) {
  return __hip_atomic_load(const_cast<float*>(p), __ATOMIC_RELAXED,
                           __HIP_MEMORY_SCOPE_AGENT);
}
__device__ __forceinline__ void astore_f(float* p, float v) {
  __hip_atomic_store(p, v, __ATOMIC_RELAXED, __HIP_MEMORY_SCOPE_AGENT);
}
__device__ __forceinline__ int aload_i(const int* p) {
  return __hip_atomic_load(const_cast<int*>(p), __ATOMIC_RELAXED,
                           __HIP_MEMORY_SCOPE_AGENT);
}
__device__ __forceinline__ void astore_i(int* p, int v) {
  __hip_atomic_store(p, v, __ATOMIC_RELAXED, __HIP_MEMORY_SCOPE_AGENT);
}

// ---------------------------------------------------------------------------
// Kernel 1: transpose x [B][T][F] -> xq [T][8][F][4]  (quad-blocked batch)
// ---------------------------------------------------------------------------
__global__ __launch_bounds__(256) void transpose_x(const float* __restrict__ x,
                                                   float* __restrict__ xq) {
  __shared__ float s[32][33];
  const int f0 = blockIdx.x * 32;
  const int t  = blockIdx.y;
  const int i  = threadIdx.x;
  const int lo = i & 31;
  const int g8 = i >> 5;  // 0..7
#pragma unroll
  for (int qq = 0; qq < 4; ++qq) {
    const int b = g8 * 4 + qq;
    const int f = f0 + lo;
    float v = 0.f;
    if (f < kF) v = x[((size_t)b * kT + t) * kF + f];
    s[b][lo] = v;
  }
  __syncthreads();
  const int r  = lo & 3;
  const int fl = lo >> 2;  // 0..7
#pragma unroll
  for (int it = 0; it < 4; ++it) {
    const int f = f0 + fl + 8 * it;
    if (f < kF)
      xq[((size_t)(t * 8 + g8) * kF + f) * 4 + r] = s[g8 * 4 + r][fl + 8 * it];
  }
}

// ---------------------------------------------------------------------------
// Kernel 2: persistent GRU. Column math BIT-EXACT rounds 3/6/7 (passing).
// Changes vs round 7 (perf-only, mapping/sync):
//  * 256-thread blocks (1 wave/SIMD, launch_bounds(256,1)) -> VGPR budget
//    doubles; the 128-VGPR vA/vB input staging stays live across ALL 8
//    columns of a unit (no rematerialized L3 reload chains).
//    8 units = 8 batch-quads; each unit does the 8 columns sequentially.
//  * RMW-free barrier: per-block monotone flag STORE (parallel, no atomic
//    serialization); block 0 wave 0 sweeps 192 flags lane-parallel and
//    publishes root = p+1; others poll root. No leaf fetch_add chains.
// ---------------------------------------------------------------------------
struct GruParams {
  const float* xq;       // [T][8][513][4]
  const float* wih[3];   // [3H][KA]
  const float* whh[3];   // [3H][H]
  const float* bih[3];
  const float* bhh[3];
  float* h[3][2];        // quad-blocked [8][512][4]
  float* out_h;          // [B*T][H]
  int* flags;            // [192] monotone per-block phase counters
  int* root;             // [16] (line 0) monotone published phase
};

__device__ __forceinline__ void fma4(float a[4], float w, float4 v) {
  a[0] = fmaf(w, v.x, a[0]);
  a[1] = fmaf(w, v.y, a[1]);
  a[2] = fmaf(w, v.z, a[2]);
  a[3] = fmaf(w, v.w, a[3]);
}

// branchless a[s] for s in 0..3 (exact select; no value change)
__device__ __forceinline__ float pick4(const float a[4], int s) {
  const float lo = (s & 1) ? a[1] : a[0];
  const float hi = (s & 1) ? a[3] : a[2];
  return (s & 2) ? hi : lo;
}

__global__ __launch_bounds__(256, 1) void gru_seq(GruParams P) {
  // weights: segA rows (g*8+c)*520, segB at +12480; biases at 24960 (48)
  __shared__ float wlds[25008];  // 100.0 KB

  const int tid = threadIdx.x;
  const int ks  = tid & 31;        // lane k-slice (round-3 semantics)
  const int q   = tid >> 5;        // unit = batch quad 0..7
  const int Lb  = blockIdx.x >> 6; // this block's layer 0..2
  const int jc0 = (blockIdx.x & 63) * 8;

  // ---- one-time weight + bias preload into LDS (this layer, 8 columns) ----
  {
    const float* wihL = P.wih[Lb];
    const float* whhL = P.whh[Lb];
    const int KA = (Lb == 0) ? kF : kH;
    for (int g = 0; g < 3; ++g)
      for (int c = 0; c < 8; ++c) {
        const int row = g * 8 + c;
        const float* sA = wihL + (size_t)(g * kH + jc0 + c) * KA;
        float* dA = &wlds[row * 520];
        for (int k = tid; k < KA; k += 256) dA[k] = sA[k];
        const float* sB = whhL + (size_t)(g * kH + jc0 + c) * kH;
        float* dB = &wlds[12480 + row * 520];
        for (int k = tid; k < kH; k += 256) dB[k] = sB[k];
      }
    if (tid < 48) {
      const int s2 = tid / 24;          // 0 = ih, 1 = hh
      const int g  = (tid % 24) / 8;
      const int c  = tid & 7;
      const float* src = s2 ? P.bhh[Lb] : P.bih[Lb];
      wlds[24960 + tid] = src[g * kH + jc0 + c];
    }
  }
  __syncthreads();

  for (int p = 0; p < kPhases; ++p) {
    const int wp = p & 1;
    const int rp = wp ^ 1;
    const int t = p - Lb;
    if (t >= 0 && t < kT) {
      const float* inB = P.h[Lb][rp] + q * (kH * 4);

      // ---- load this lane's input quads ONCE (live across all 8 cols) ----
      float4 vA[4][4], vB[4][4];
      if (Lb == 0) {
        const float* inA = P.xq + ((size_t)t * 8 + q) * (kF * 4);
#pragma unroll
        for (int i = 0; i < 4; ++i) {
          const int k = 4 * ks + 128 * i;
#pragma unroll
          for (int m = 0; m < 4; ++m) {
            vA[i][m] = *reinterpret_cast<const float4*>(inA + (size_t)(k + m) * 4);
            vB[i][m] = aload_f4(inB + (size_t)(k + m) * 4);
          }
        }
      } else {
        const float* inA = P.h[Lb - 1][rp] + q * (kH * 4);
#pragma unroll
        for (int i = 0; i < 4; ++i) {
          const int k = 4 * ks + 128 * i;
#pragma unroll
          for (int m = 0; m < 4; ++m) {
            vA[i][m] = aload_f4(inA + (size_t)(k + m) * 4);
            vB[i][m] = aload_f4(inB + (size_t)(k + m) * 4);
          }
        }
      }
      float4 vE = make_float4(0.f, 0.f, 0.f, 0.f);
      if (Lb == 0 && ks == 0)
        vE = *reinterpret_cast<const float4*>(P.xq + ((size_t)t * 8 + q) * (kF * 4)
                                              + (size_t)512 * 4);

      // ---- 8 columns sequentially; per-column math bit-exact r3/6/7 ----
#pragma unroll 1
      for (int col = 0; col < 8; ++col) {
        const int jg  = jc0 + col;       // global column
        const float* wa0 = &wlds[(0 * 8 + col) * 520];
        const float* wa1 = &wlds[(1 * 8 + col) * 520];
        const float* wa2 = &wlds[(2 * 8 + col) * 520];
        const float* wb0 = &wlds[12480 + (0 * 8 + col) * 520];
        const float* wb1 = &wlds[12480 + (1 * 8 + col) * 520];
        const float* wb2 = &wlds[12480 + (2 * 8 + col) * 520];

        float aR[4]  = {0.f, 0.f, 0.f, 0.f};
        float aZ[4]  = {0.f, 0.f, 0.f, 0.f};
        float aNi[4] = {0.f, 0.f, 0.f, 0.f};
        float aNh[4] = {0.f, 0.f, 0.f, 0.f};

        // segment A: w_ih . in
#pragma unroll
        for (int i = 0; i < 4; ++i) {
          const int k = 4 * ks + 128 * i;
          const float4 w0 = *reinterpret_cast<const float4*>(wa0 + k);
          const float4 w1 = *reinterpret_cast<const float4*>(wa1 + k);
          const float4 w2 = *reinterpret_cast<const float4*>(wa2 + k);
          fma4(aR, w0.x, vA[i][0]);  fma4(aR, w0.y, vA[i][1]);
          fma4(aR, w0.z, vA[i][2]);  fma4(aR, w0.w, vA[i][3]);
          fma4(aZ, w1.x, vA[i][0]);  fma4(aZ, w1.y, vA[i][1]);
          fma4(aZ, w1.z, vA[i][2]);  fma4(aZ, w1.w, vA[i][3]);
          fma4(aNi, w2.x, vA[i][0]); fma4(aNi, w2.y, vA[i][1]);
          fma4(aNi, w2.z, vA[i][2]); fma4(aNi, w2.w, vA[i][3]);
        }
        if (Lb == 0 && ks == 0) {  // edge column k = 512 (after segA)
          fma4(aR,  wa0[512], vE);
          fma4(aZ,  wa1[512], vE);
          fma4(aNi, wa2[512], vE);
        }
        // segment B: w_hh . h_old (R,Z chain into same accumulators)
#pragma unroll
        for (int i = 0; i < 4; ++i) {
          const int k = 4 * ks + 128 * i;
          const float4 w0 = *reinterpret_cast<const float4*>(wb0 + k);
          const float4 w1 = *reinterpret_cast<const float4*>(wb1 + k);
          const float4 w2 = *reinterpret_cast<const float4*>(wb2 + k);
          fma4(aR, w0.x, vB[i][0]);  fma4(aR, w0.y, vB[i][1]);
          fma4(aR, w0.z, vB[i][2]);  fma4(aR, w0.w, vB[i][3]);
          fma4(aZ, w1.x, vB[i][0]);  fma4(aZ, w1.y, vB[i][1]);
          fma4(aZ, w1.z, vB[i][2]);  fma4(aZ, w1.w, vB[i][3]);
          fma4(aNh, w2.x, vB[i][0]); fma4(aNh, w2.y, vB[i][1]);
          fma4(aNh, w2.z, vB[i][2]); fma4(aNh, w2.w, vB[i][3]);
        }
        // butterfly all-reduce over the 32-lane half (exact round-3 order)
#pragma unroll
        for (int m = 1; m <= 16; m <<= 1) {
#pragma unroll
          for (int c2 = 0; c2 < 4; ++c2) {
            aR[c2]  += __shfl_xor(aR[c2],  m);
            aZ[c2]  += __shfl_xor(aZ[c2],  m);
            aNi[c2] += __shfl_xor(aNi[c2], m);
            aNh[c2] += __shfl_xor(aNh[c2], m);
          }
        }
        // gate combine: lanes ks<4 handle batch b = q*4 + ks
        if (ks < 4) {
          const float bi0 = wlds[24960 + 0 * 8 + col];
          const float bi1 = wlds[24960 + 1 * 8 + col];
          const float bi2 = wlds[24960 + 2 * 8 + col];
          const float bh0 = wlds[24960 + 24 + 0 * 8 + col];
          const float bh1 = wlds[24960 + 24 + 1 * 8 + col];
          const float bh2 = wlds[24960 + 24 + 2 * 8 + col];
          const float sR  = pick4(aR, ks);
          const float sZ  = pick4(aZ, ks);
          const float sNi = pick4(aNi, ks);
          const float sNh = pick4(aNh, ks);
          const float r = 1.f / (1.f + expf(-(sR + bi0 + bh0)));
          const float z = 1.f / (1.f + expf(-(sZ + bi1 + bh1)));
          const float n = tanhf(sNi + bi2 + r * (sNh + bh2));
          const float ho = aload_f(inB + jg * 4 + ks);
          const float hn = (1.f - z) * n + z * ho;
          astore_f(&P.h[Lb][wp][(q * kH + jg) * 4 + ks], hn);
          if (Lb == 2)
            P.out_h[((size_t)(q * 4 + ks) * kT + t) * kH + jg] = hn;
        }
      }
    }
    // ---- RMW-free grid barrier ----
    // syncthreads drains every wave's sc-stores (vmcnt 0 before s_barrier)
    // -> h writes are at the coherence point before the flag publishes.
    __syncthreads();
    if (tid == 0) astore_i(&P.flags[blockIdx.x], p + 1);  // parallel arrivals
    if (blockIdx.x == 0) {
      if (tid < 64) {  // wave 0: lane-parallel sweep of all 192 flags
        for (;;) {
          const bool ok = (aload_i(&P.flags[tid])       >= p + 1) &&
                          (aload_i(&P.flags[64 + tid])  >= p + 1) &&
                          (aload_i(&P.flags[128 + tid]) >= p + 1);
          if (__ballot(ok) == ~0ull) break;
        }
        if (tid == 0) astore_i(P.root, p + 1);  // publish
      }
    } else if (tid == 0) {
      while (aload_i(P.root) < p + 1) __builtin_amdgcn_s_sleep(1);
    }
    __syncthreads();
  }
}

// ---------------------------------------------------------------------------
// Kernel 3: fused head (unchanged; bit-identical to rounds 1/3/6/7).
// ---------------------------------------------------------------------------
__global__ __launch_bounds__(256) void out_mask(
    const float* __restrict__ A,   // out_h [B*T][H]
    const float* __restrict__ w1, const float* __restrict__ bl1,
    const float* __restrict__ w2, const float* __restrict__ bl2,
    const float* __restrict__ x,   // [B*T][F]
    float* __restrict__ o1, float* __restrict__ o2) {
  __shared__ float As[16][68], W1s[16][68], W2s[16][68];
  const int tid = threadIdx.x;
  const int n0 = blockIdx.x * 64;
  const int m0 = blockIdx.y * 64;
  const int tn = tid & 15, tm = tid >> 4;
  const int lr = tid >> 2;
  const int lk = (tid & 3) * 4;

  float ac1[4][4], ac2[4][4];
#pragma unroll
  for (int mm = 0; mm < 4; ++mm)
#pragma unroll
    for (int nn = 0; nn < 4; ++nn) { ac1[mm][nn] = 0.f; ac2[mm][nn] = 0.f; }

  for (int k0 = 0; k0 < kH; k0 += 16) {
    const float4 av = *reinterpret_cast<const float4*>(A + (size_t)(m0 + lr) * kH + k0 + lk);
    const int fA = n0 + lr;
    float4 wv1 = make_float4(0.f, 0.f, 0.f, 0.f);
    float4 wv2 = make_float4(0.f, 0.f, 0.f, 0.f);
    if (fA < kF) {
      wv1 = *reinterpret_cast<const float4*>(w1 + (size_t)fA * kH + k0 + lk);
      wv2 = *reinterpret_cast<const float4*>(w2 + (size_t)fA * kH + k0 + lk);
    }
    __syncthreads();
    As[lk + 0][lr] = av.x;  As[lk + 1][lr] = av.y;  As[lk + 2][lr] = av.z;  As[lk + 3][lr] = av.w;
    W1s[lk + 0][lr] = wv1.x; W1s[lk + 1][lr] = wv1.y; W1s[lk + 2][lr] = wv1.z; W1s[lk + 3][lr] = wv1.w;
    W2s[lk + 0][lr] = wv2.x; W2s[lk + 1][lr] = wv2.y; W2s[lk + 2][lr] = wv2.z; W2s[lk + 3][lr] = wv2.w;
    __syncthreads();
#pragma unroll
    for (int kk = 0; kk < 16; ++kk) {
      const float4 a = *reinterpret_cast<const float4*>(&As[kk][tm * 4]);
      const float4 uu4 = *reinterpret_cast<const float4*>(&W1s[kk][tn * 4]);
      const float4 vv4 = *reinterpret_cast<const float4*>(&W2s[kk][tn * 4]);
      const float aa[4] = {a.x, a.y, a.z, a.w};
      const float uu[4] = {uu4.x, uu4.y, uu4.z, uu4.w};
      const float vv[4] = {vv4.x, vv4.y, vv4.z, vv4.w};
#pragma unroll
      for (int mm = 0; mm < 4; ++mm)
#pragma unroll
        for (int nn = 0; nn < 4; ++nn) {
          ac1[mm][nn] += aa[mm] * uu[nn];
          ac2[mm][nn] += aa[mm] * vv[nn];
        }
    }
  }
#pragma unroll
  for (int mm = 0; mm < 4; ++mm) {
    const int row = m0 + tm * 4 + mm;
#pragma unroll
    for (int nn = 0; nn < 4; ++nn) {
      const int f = n0 + tn * 4 + nn;
      if (f < kF) {
        const float s1 = fmaxf(ac1[mm][nn] + bl1[f], 0.f);
        const float s2 = fmaxf(ac2[mm][nn] + bl2[f], 0.f);
        const float inv = 1.f / (s1 + s2 + 1e-16f);
        const float xv = x[(size_t)row * kF + f];
        o1[(size_t)row * kF + f] = s1 * inv * xv;
        o2[(size_t)row * kF + f] = s2 * inv * xv;
      }
    }
  }
}

// ---------------------------------------------------------------------------
extern "C" void kernel_launch(void* const* d_in, const int* in_sizes, int n_in,
                              void* d_out, int out_size, void* d_ws, size_t ws_size,
                              hipStream_t stream) {
  const float* x = (const float*)d_in[0];
  GruParams P;
  P.wih[0] = (const float*)d_in[1];  P.whh[0] = (const float*)d_in[2];
  P.bih[0] = (const float*)d_in[3];  P.bhh[0] = (const float*)d_in[4];
  P.wih[1] = (const float*)d_in[5];  P.whh[1] = (const float*)d_in[6];
  P.bih[1] = (const float*)d_in[7];  P.bhh[1] = (const float*)d_in[8];
  P.wih[2] = (const float*)d_in[9];  P.whh[2] = (const float*)d_in[10];
  P.bih[2] = (const float*)d_in[11]; P.bhh[2] = (const float*)d_in[12];
  const float* w_l1 = (const float*)d_in[13];
  const float* b_l1 = (const float*)d_in[14];
  const float* w_l2 = (const float*)d_in[15];
  const float* b_l2 = (const float*)d_in[16];

  // ws layout: root[16] | flags[192] (monotone ints), then 6 quad-blocked
  // h buffers, then out_h. (208 ints = 832 B, 16B-aligned.)
  int* root = (int*)d_ws;
  int* flags = root + 16;
  float* ws = (float*)d_ws + 208;
  for (int l = 0; l < 3; ++l)
    for (int pp = 0; pp < 2; ++pp) {
      P.h[l][pp] = ws;
      ws += kH * kB;
    }
  float* out_h = ws;                                     // [B*T][H]
  P.root = root;
  P.flags = flags;
  P.out_h = out_h;

  // xq lives in the o1 half of d_out (dead until out_mask overwrites it):
  // [T][8][513][4] = 8,404,992 floats = exactly o1's size.
  float* o1 = (float*)d_out;
  float* o2 = o1 + (size_t)kB * kT * kF;
  float* xq = o1;
  P.xq = xq;

  // zero root+flags + h buffers (contiguous at ws start)
  const size_t zero_bytes = (size_t)208 * sizeof(int)
                          + (size_t)6 * kH * kB * sizeof(float);
  hipMemsetAsync(d_ws, 0, zero_bytes, stream);

  transpose_x<<<dim3(17, kT), 256, 0, stream>>>(x, xq);

  void* args[] = { (void*)&P };
  hipLaunchCooperativeKernel((void*)gru_seq, dim3(192), dim3(256), args, 0u, stream);

  out_mask<<<dim3(9, 256), 256, 0, stream>>>(out_h, w_l1, b_l1, w_l2, b_l2, x, o1, o2);
}